// Round 11
// baseline (374.895 us; speedup 1.0000x reference)
//
#include <hip/hip_runtime.h>
#include <hip/hip_bf16.h>
#include <hip/hip_fp16.h>

#define NEG_SLOPE 0.2f
#define BW 256       // dst-nodes per bucket
#define MAXB 512     // max bucket count
#define BSTRIDE 4736 // fixed per-bucket region (mean 4092 + 10 sigma), Poisson-safe

typedef __attribute__((ext_vector_type(8))) short short8;
typedef __attribute__((ext_vector_type(4))) float f32x4;
typedef __attribute__((ext_vector_type(2))) float f32x2;
typedef __attribute__((ext_vector_type(4))) unsigned u32x4;

__device__ inline float bf2f(short s) {
    union { unsigned u; float f; } v;
    v.u = ((unsigned)(unsigned short)s) << 16;
    return v.f;
}
__device__ inline short f2bf(float f) {
    __hip_bfloat16 h = __float2bfloat16(f);
    return (short)*reinterpret_cast<unsigned short*>(&h);
}
__device__ inline float lo_bf(unsigned u) {
    union { unsigned u; float f; } v;
    v.u = u << 16;
    return v.f;
}
__device__ inline float hi_bf(unsigned u) {
    union { unsigned u; float f; } v;
    v.u = u & 0xFFFF0000u;
    return v.f;
}
// pack (src, p>=0) into one u32: src<<15 | (bf16 bits of p, sign dropped)
__device__ inline unsigned pack_sb(int s, float p) {
    union { float f; unsigned u; } v;
    v.f = p;
    return ((unsigned)s << 15) | ((v.u >> 16) & 0x7FFFu);
}
__device__ inline float unpack_b(unsigned u) {
    union { unsigned u; float f; } v;
    v.u = (u & 0x7FFFu) << 16;
    return v.f;
}
__device__ inline void gload16(const void* g, void* lds) {
    __builtin_amdgcn_global_load_lds((const __attribute__((address_space(1))) void*)g,
                                     (__attribute__((address_space(3))) void*)lds, 16, 0, 0);
}

// ---------------- K1: bucket partition (fixed-stride, single pass) + weight convert -------

__global__ __launch_bounds__(256) void bpart_cvt_kernel(
    const int* __restrict__ dst, const int* __restrict__ src, int* __restrict__ bcur,
    unsigned* __restrict__ tmp, int E, int NB, int GE,
    const float* __restrict__ W0, __hip_bfloat16* __restrict__ Wt0,
    const float* __restrict__ W1, __hip_bfloat16* __restrict__ Wt1) {
    int tid = threadIdx.x;
    if ((int)blockIdx.x >= GE) {
        int i = (blockIdx.x - GE) * 256 + tid;
        if (i < 256 * 128) {
            int k = i / 128, n = i % 128;
            Wt0[(size_t)n * 256 + k] = __float2bfloat16(W0[i]);
        } else if (i < 256 * 128 + 128 * 128) {
            int j = i - 256 * 128;
            int k = j / 128, n = j % 128;
            Wt1[(size_t)n * 128 + k] = __float2bfloat16(W1[j]);
        }
        return;
    }
    __shared__ int h[MAXB], h2[MAXB], base[MAXB];
    for (int i = tid; i < NB; i += 256) { h[i] = 0; h2[i] = 0; }
    __syncthreads();
    int e0 = blockIdx.x * 4096;
    unsigned pk[16];
    short bb[16];
#pragma unroll
    for (int i = 0; i < 16; ++i) {
        int e = e0 + i * 256 + tid;
        bool valid = e < E;
        int d = valid ? dst[e] : 0;
        int s = valid ? src[e] : 0;
        bb[i] = valid ? (short)(d >> 8) : (short)-1;
        pk[i] = (unsigned)s | ((unsigned)(d & 255) << 17);
        if (valid) atomicAdd(&h[d >> 8], 1);
    }
    __syncthreads();
    for (int i = tid; i < NB; i += 256)
        base[i] = h[i] ? (i * BSTRIDE + atomicAdd(&bcur[i], h[i])) : 0;
    __syncthreads();
#pragma unroll
    for (int i = 0; i < 16; ++i) {
        if (bb[i] >= 0) {
            int pos = base[bb[i]] + atomicAdd(&h2[bb[i]], 1);
            if (pos < (bb[i] + 1) * BSTRIDE) tmp[pos] = pk[i];  // clamp (Poisson 10-sigma)
        }
    }
}

// ---------------- shared GEMM body: C[M,128] = A[M,K] @ Bt[128,K]^T + fused el/er ----------

template <bool CVT_A>
__device__ void gemm_body(short* smem, int bm, const void* __restrict__ Av,
                          const __hip_bfloat16* __restrict__ Bt,
                          __hip_bfloat16* __restrict__ Cb,
                          const float* __restrict__ al, const float* __restrict__ ar,
                          float* __restrict__ el, float* __restrict__ er, int M, int K) {
    const int tid = threadIdx.x;
    const int lane = tid & 63;
    const int w = tid >> 6;
    const int wr = w >> 1, wc = w & 1;
    f32x4 acc[4][4];
#pragma unroll
    for (int m = 0; m < 4; ++m)
#pragma unroll
        for (int n = 0; n < 4; ++n) acc[m][n] = 0.f;

    for (int k0 = 0; k0 < K; k0 += 32) {
#pragma unroll
        for (int i = 0; i < 2; ++i) {
            const int c = (w * 2 + i) * 64 + lane;
            const int row = c >> 2;
            const int kpg = (c & 3) ^ (row & 3);
            int grow = bm + row;
            grow = grow < M ? grow : M - 1;
            if (CVT_A) {
                const float* gp = (const float*)Av + (size_t)grow * K + k0 + kpg * 8;
                f32x4 f0 = __builtin_nontemporal_load((const f32x4*)gp);
                f32x4 f1 = __builtin_nontemporal_load((const f32x4*)(gp + 4));
                short8 v;
                v[0] = f2bf(f0[0]); v[1] = f2bf(f0[1]); v[2] = f2bf(f0[2]); v[3] = f2bf(f0[3]);
                v[4] = f2bf(f1[0]); v[5] = f2bf(f1[1]); v[6] = f2bf(f1[2]); v[7] = f2bf(f1[3]);
                *(short8*)&smem[c * 8] = v;
            } else {
                const __hip_bfloat16* gp =
                    (const __hip_bfloat16*)Av + (size_t)grow * K + k0 + kpg * 8;
                gload16(gp, &smem[(w * 2 + i) * 512]);
            }
        }
#pragma unroll
        for (int i = 0; i < 2; ++i) {
            const int c = (w * 2 + i) * 64 + lane;
            const int col = c >> 2;
            const int kpg = (c & 3) ^ (col & 3);
            const __hip_bfloat16* gp = Bt + (size_t)col * K + k0 + kpg * 8;
            gload16(gp, &smem[4096 + (w * 2 + i) * 512]);
        }
        __syncthreads();
        short8 a[4], b[4];
        const int kp = lane >> 4;
#pragma unroll
        for (int m = 0; m < 4; ++m) {
            const int row = wr * 64 + m * 16 + (lane & 15);
            a[m] = *(const short8*)&smem[row * 32 + ((kp ^ (row & 3)) << 3)];
        }
#pragma unroll
        for (int n = 0; n < 4; ++n) {
            const int col = wc * 64 + n * 16 + (lane & 15);
            b[n] = *(const short8*)&smem[4096 + col * 32 + ((kp ^ (col & 3)) << 3)];
        }
#pragma unroll
        for (int m = 0; m < 4; ++m)
#pragma unroll
            for (int n = 0; n < 4; ++n)
                acc[m][n] = __builtin_amdgcn_mfma_f32_16x16x32_bf16(a[m], b[n], acc[m][n], 0, 0, 0);
        __syncthreads();
    }
    // ---- C store (bf16) ----
#pragma unroll
    for (int m = 0; m < 4; ++m)
#pragma unroll
        for (int j = 0; j < 4; ++j) {
            int row = bm + wr * 64 + m * 16 + (lane >> 4) * 4 + j;
            if (row >= M) continue;
#pragma unroll
            for (int n = 0; n < 4; ++n) {
                int col = wc * 64 + n * 16 + (lane & 15);
                Cb[(size_t)row * 128 + col] = __float2bfloat16(acc[m][n][j]);
            }
        }
    // ---- fused el/er epilogue ----
    const int lx = lane & 15;
    const float al00 = al[2 * wc * 32 + lx],        al01 = al[2 * wc * 32 + 16 + lx];
    const float al10 = al[(2 * wc + 1) * 32 + lx],  al11 = al[(2 * wc + 1) * 32 + 16 + lx];
    const float ar00 = ar[2 * wc * 32 + lx],        ar01 = ar[2 * wc * 32 + 16 + lx];
    const float ar10 = ar[(2 * wc + 1) * 32 + lx],  ar11 = ar[(2 * wc + 1) * 32 + 16 + lx];
#pragma unroll
    for (int m = 0; m < 4; ++m) {
#pragma unroll
        for (int j = 0; j < 4; ++j) {
            int row = bm + wr * 64 + m * 16 + (lane >> 4) * 4 + j;
            float pl0 = acc[m][0][j] * al00 + acc[m][1][j] * al01;
            float pr0 = acc[m][0][j] * ar00 + acc[m][1][j] * ar01;
            float pl1 = acc[m][2][j] * al10 + acc[m][3][j] * al11;
            float pr1 = acc[m][2][j] * ar10 + acc[m][3][j] * ar11;
#pragma unroll
            for (int off = 1; off < 16; off <<= 1) {
                pl0 += __shfl_xor(pl0, off);
                pr0 += __shfl_xor(pr0, off);
                pl1 += __shfl_xor(pl1, off);
                pr1 += __shfl_xor(pr1, off);
            }
            if (lx == 0 && row < M) {
                el[row * 4 + 2 * wc] = pl0;
                el[row * 4 + 2 * wc + 1] = pl1;
                er[row * 4 + 2 * wc] = pr0;
                er[row * 4 + 2 * wc + 1] = pr1;
            }
        }
    }
}

// ---------------- bsort body: per-bucket counting sort -> csr + off_beg/off_end ------------

__device__ void bsort_body(int* lds, int b, const unsigned* __restrict__ tmp,
                           const int* __restrict__ bcur, int* __restrict__ csr,
                           int* __restrict__ off_beg, int* __restrict__ off_end, int N) {
    int* cnt = lds;
    int* cur = lds + 256;
    int tid = threadIdx.x;
    int Rb = b * BSTRIDE;
    int cnt_b = bcur[b];
    if (cnt_b > BSTRIDE) cnt_b = BSTRIDE;
    int Rend = Rb + cnt_b;
    cnt[tid] = 0;
    __syncthreads();
    for (int i = Rb + tid; i < Rend; i += 256) atomicAdd(&cnt[tmp[i] >> 17], 1);
    __syncthreads();
    int v = cnt[tid];
    cur[tid] = v;
    __syncthreads();
    int x = v;
    for (int off = 1; off < 256; off <<= 1) {
        int y = (tid >= off) ? cur[tid - off] : 0;
        __syncthreads();
        x += y;
        cur[tid] = x;
        __syncthreads();
    }
    int excl = x - v;
    int g = b * BW + tid;
    int cbase = Rb + excl;
    if (g < N) {
        off_beg[g] = cbase;
        off_end[g] = cbase + v;
    }
    cur[tid] = cbase;
    __syncthreads();
    for (int i = Rb + tid; i < Rend; i += 256) {
        unsigned p = tmp[i];
        int pos = atomicAdd(&cur[p >> 17], 1);
        csr[pos] = (int)(p & 0x1FFFFu);
    }
}

// ---------------- K2: layer-0 GEMM (CVT_A) || bucket sort, one launch ----------------------

__global__ __launch_bounds__(256) void gemm0_bsort_kernel(
    const float* __restrict__ feats, const __hip_bfloat16* __restrict__ Wt0,
    __hip_bfloat16* __restrict__ Cb, const float* __restrict__ al,
    const float* __restrict__ ar, float* __restrict__ el, float* __restrict__ er,
    int M, int gM,
    const unsigned* __restrict__ tmp, const int* __restrict__ bcur, int* __restrict__ csr,
    int* __restrict__ off_beg, int* __restrict__ off_end, int N) {
    __shared__ __align__(16) short smem[8192];
    if ((int)blockIdx.x < gM) {
        gemm_body<true>(smem, blockIdx.x * 128, feats, Wt0, Cb, al, ar, el, er, M, 256);
    } else {
        bsort_body((int*)smem, blockIdx.x - gM, tmp, bcur, csr, off_beg, off_end, N);
    }
}

// ---------------- layer-1 GEMM ----------------

__global__ __launch_bounds__(256) void gemm1_kernel(
    const __hip_bfloat16* __restrict__ A, const __hip_bfloat16* __restrict__ Wt1,
    __hip_bfloat16* __restrict__ Cb, const float* __restrict__ al,
    const float* __restrict__ ar, float* __restrict__ el, float* __restrict__ er, int M) {
    __shared__ __align__(16) short smem[8192];
    gemm_body<false>(smem, blockIdx.x * 128, A, Wt1, Cb, al, ar, el, er, M, 128);
}

// ---------------- skinny GEMM layer2 + fused el/er: C[M,64], cols 40..63 unwritten ---------

__global__ __launch_bounds__(256) void gemm40_kernel(const __hip_bfloat16* __restrict__ A,
                                                     const float* __restrict__ W,
                                                     const float* __restrict__ al,
                                                     const float* __restrict__ ar,
                                                     __hip_bfloat16* __restrict__ C,
                                                     float* __restrict__ el,
                                                     float* __restrict__ er, int M) {
    int rowb = blockIdx.x * 256 + threadIdx.x;
    int row = rowb < M ? rowb : M - 1;
    float acc[40];
#pragma unroll
    for (int c = 0; c < 40; ++c) acc[c] = 0.f;
    const short8* ap = (const short8*)(A + (size_t)row * 128);
#pragma unroll 1
    for (int kc = 0; kc < 16; ++kc) {
        short8 v = ap[kc];
#pragma unroll
        for (int j = 0; j < 8; ++j) {
            float f = bf2f(v[j]);
            const float* wrow = W + (kc * 8 + j) * 40;
#pragma unroll
            for (int c = 0; c < 40; ++c) acc[c] += f * wrow[c];
        }
    }
    if (rowb < M) {
        float sl = 0.f, sr = 0.f;
#pragma unroll
        for (int c = 0; c < 40; ++c) {
            __hip_bfloat16 hb = __float2bfloat16(acc[c]);
            float hv = __bfloat162float(hb);
            C[(size_t)rowb * 64 + c] = hb;
            sl += hv * al[c];
            sr += hv * ar[c];
        }
        el[rowb] = sl;
        er[rowb] = sr;
    }
}

// ---------------- fused attention+aggregation, H=4 D=32, persistent blocks -----------------
// edge phase: lane = es*4+ha (16 edges x 4 heads).
// consume: quarter q=lane>>4 handles edges e≡q (mod 4); ql=lane&15 covers cols ql*8..+7,
// head hq=ql>>2. Cross-quarter combine via shfl_xor(16),(32).

__global__ __launch_bounds__(256) void gat_agg4_kernel(
    const int* __restrict__ off_beg, const int* __restrict__ off_end,
    const int* __restrict__ csr_src, const float* __restrict__ el,
    const float* __restrict__ er, const __hip_bfloat16* __restrict__ hfeat,
    float* __restrict__ outf, unsigned* __restrict__ outb, int N) {
    int lane = threadIdx.x & 63;
    int wv = threadIdx.x >> 6;
    int ha = lane & 3;
    int es = lane >> 2;
    int q = lane >> 4;
    int ql = lane & 15;
    int hq = ql >> 2;
    const __hip_bfloat16* hcol = hfeat + ql * 8;
    for (int g = blockIdx.x; g * 4 < N; g += gridDim.x) {
        int node = g * 4 + wv;
        if (node >= N) continue;
        int beg = off_beg[node], end = off_end[node];
        float ern = er[node * 4 + ha];
        float d_acc = 0.f;
        float acc[8] = {0.f, 0.f, 0.f, 0.f, 0.f, 0.f, 0.f, 0.f};
        for (int base = beg; base < end; base += 16) {
            int b = base + es;
            bool valid = b < end;
            int s = valid ? csr_src[b] : 0;
            float x = -1e30f;
            if (valid) {
                x = el[s * 4 + ha] + ern;
                x = x > 0.f ? x : NEG_SLOPE * x;
            }
            float p = __expf(x);  // 0 for invalid edges
            float pv[4];
            int rv[4];
#pragma unroll
            for (int k = 0; k < 4; ++k) {
                int e = q + 4 * k;  // e <= 15
                pv[k] = __shfl(p, (e << 2) | hq);
                rv[k] = __shfl(s, e << 2);
            }
            u32x4 hv[4];
#pragma unroll
            for (int k = 0; k < 4; ++k)
                hv[k] = *(const u32x4*)(hcol + (size_t)rv[k] * 128);
#pragma unroll
            for (int k = 0; k < 4; ++k) {
                float a = pv[k];
                d_acc += a;
#pragma unroll
                for (int i = 0; i < 4; ++i) {
                    acc[2 * i] += lo_bf(hv[k][i]) * a;
                    acc[2 * i + 1] += hi_bf(hv[k][i]) * a;
                }
            }
        }
        // combine quarters
#pragma unroll
        for (int j = 0; j < 8; ++j) {
            acc[j] += __shfl_xor(acc[j], 16);
            acc[j] += __shfl_xor(acc[j], 32);
        }
        d_acc += __shfl_xor(d_acc, 16);
        d_acc += __shfl_xor(d_acc, 32);
        float idn = 1.f / fmaxf(d_acc, 1e-9f);
        if (q == 0) {
            float v[8];
#pragma unroll
            for (int j = 0; j < 8; ++j) {
                float t = acc[j] * idn;
                v[j] = t > 0.f ? t : __expf(t) - 1.f;  // ELU
            }
            f32x4 fo0 = {v[0], v[1], v[2], v[3]};
            f32x4 fo1 = {v[4], v[5], v[6], v[7]};
            __builtin_nontemporal_store(fo0, (f32x4*)(outf + (size_t)node * 128 + ql * 8));
            __builtin_nontemporal_store(fo1, (f32x4*)(outf + (size_t)node * 128 + ql * 8 + 4));
            u32x4 uo;
#pragma unroll
            for (int i = 0; i < 4; ++i)
                uo[i] = (unsigned)(unsigned short)f2bf(v[2 * i]) |
                        ((unsigned)(unsigned short)f2bf(v[2 * i + 1]) << 16);
            *(u32x4*)(outb + (size_t)node * 64 + ql * 4) = uo;
        }
    }
}

// ---------------- fused attention+aggregation, H=1, persistent blocks ----------------------

__global__ __launch_bounds__(256) void gat_agg1_kernel(
    const int* __restrict__ off_beg, const int* __restrict__ off_end,
    const int* __restrict__ csr_src, const float* __restrict__ el,
    const float* __restrict__ er, const __hip_bfloat16* __restrict__ hfeat,
    float* __restrict__ logits, int N) {
    int lane = threadIdx.x & 63;
    int wv = threadIdx.x >> 6;
    int cl = lane & 31;
    int half = lane >> 5;
    bool active = cl < 20;
    const __hip_bfloat16* hcol = hfeat + cl * 2;
    for (int g = blockIdx.x; g * 4 < N; g += gridDim.x) {
        int node = g * 4 + wv;
        if (node >= N) continue;
        int beg = off_beg[node], end = off_end[node];
        float ern = er[node];
        float d_acc = 0.f;
        float acc0 = 0.f, acc1 = 0.f;
        for (int base = beg; base < end; base += 64) {
            int b = base + lane;
            bool valid = b < end;
            int s = valid ? csr_src[b] : 0;
            float x = -1e30f;
            if (valid) {
                x = el[s] + ern;
                x = x > 0.f ? x : NEG_SLOPE * x;
            }
            float p = __expf(x);  // 0 for invalid
            unsigned u_mine = pack_sb(s, p);
            int cnt = min(64, end - base);
            for (int sb = 0; sb < cnt; sb += 16) {
                unsigned uk[8];
#pragma unroll
                for (int k = 0; k < 8; ++k) {
                    int e = sb + half + 2 * k;
                    uk[k] = __shfl(u_mine, e & 63);
                    if (e >= cnt) uk[k] &= ~0x7FFFu;  // alpha -> 0
                }
                unsigned hv[8];
#pragma unroll
                for (int k = 0; k < 8; ++k)
                    hv[k] = active ? *(const unsigned*)(hcol + ((size_t)(uk[k] >> 15)) * 64) : 0u;
#pragma unroll
                for (int k = 0; k < 8; ++k) {
                    float a = unpack_b(uk[k]);
                    d_acc += a;
                    acc0 += lo_bf(hv[k]) * a;
                    acc1 += hi_bf(hv[k]) * a;
                }
            }
        }
        acc0 += __shfl_xor(acc0, 32);
        acc1 += __shfl_xor(acc1, 32);
        d_acc += __shfl_xor(d_acc, 32);
        float idn = 1.f / fmaxf(d_acc, 1e-9f);
        if (half == 0 && active) {
            f32x2 fo = {acc0 * idn, acc1 * idn};
            __builtin_nontemporal_store(fo, (f32x2*)(logits + (size_t)node * 40 + cl * 2));
        }
    }
}

// ---------------- launch ----------------

extern "C" void kernel_launch(void* const* d_in, const int* in_sizes, int n_in,
                              void* d_out, int out_size, void* d_ws, size_t ws_size,
                              hipStream_t stream) {
    const float* feats = (const float*)d_in[0];
    const int* src = (const int*)d_in[1];
    const int* dst = (const int*)d_in[2];
    const float* W0 = (const float*)d_in[3];
    const float* al0 = (const float*)d_in[4];
    const float* ar0 = (const float*)d_in[5];
    const float* W1 = (const float*)d_in[6];
    const float* al1 = (const float*)d_in[7];
    const float* ar1 = (const float*)d_in[8];
    const float* W2 = (const float*)d_in[9];
    const float* al2 = (const float*)d_in[10];
    const float* ar2 = (const float*)d_in[11];

    const int N = in_sizes[0] / 256;
    const int E = in_sizes[1];
    const int NB = (N + BW - 1) / BW;

    float* out = (float*)d_out;
    float* logits = out;
    float* h1 = out + (size_t)N * 40;
    float* h2 = h1 + (size_t)N * 128;

    char* p = (char*)d_ws;
    __hip_bfloat16* hA = (__hip_bfloat16*)p; p += (size_t)N * 128 * 2;
    __hip_bfloat16* hB = (__hip_bfloat16*)p; p += (size_t)N * 128 * 2;
    float* el = (float*)p;   p += (size_t)N * 4 * 4;
    float* er = (float*)p;   p += (size_t)N * 4 * 4;
    __hip_bfloat16* Wt0 = (__hip_bfloat16*)p; p += 128 * 256 * 2;
    __hip_bfloat16* Wt1 = (__hip_bfloat16*)p; p += 128 * 128 * 2;
    int* off_beg = (int*)p;  p += (size_t)N * 4;
    int* off_end = (int*)p;  p += (size_t)N * 4;
    int* bcur = (int*)p;     p += MAXB * 4;
    int* csr = (int*)p;      p += (size_t)NB * BSTRIDE * 4;
    unsigned* tmp = (unsigned*)hB;  // alias: hB first written by agg4-L0, after bsort reads

    const int gN256 = (N + 255) / 256;
    const int gE4096 = (E + 4095) / 4096;  // 391
    const int gM128 = (N + 127) / 128;
    const int gAggFull = (N + 3) / 4;
    const int gAgg = gAggFull < 2048 ? gAggFull : 2048;  // persistent blocks
    const int gCvt = (256 * 128 + 128 * 128 + 255) / 256;  // 192

    // ---- K1: bucket partition (fixed stride) + weight convert ----
    hipError_t _e = hipMemsetAsync(bcur, 0, MAXB * sizeof(int), stream);
    (void)_e;
    bpart_cvt_kernel<<<gE4096 + gCvt, 256, 0, stream>>>(dst, src, bcur, tmp, E, NB, gE4096,
                                                        W0, Wt0, W1, Wt1);

    // ---- K2: layer-0 GEMM || bucket sort ----
    gemm0_bsort_kernel<<<gM128 + NB, 256, 0, stream>>>(feats, Wt0, hA, al0, ar0, el, er,
                                                       N, gM128, tmp, bcur, csr,
                                                       off_beg, off_end, N);

    // ---- layer 0 aggregate ----
    gat_agg4_kernel<<<gAgg, 256, 0, stream>>>(off_beg, off_end, csr, el, er, hA, h1,
                                              (unsigned*)hB, N);

    // ---- layer 1 ----
    gemm1_kernel<<<gM128, 256, 0, stream>>>(hB, Wt1, hA, al1, ar1, el, er, N);
    gat_agg4_kernel<<<gAgg, 256, 0, stream>>>(off_beg, off_end, csr, el, er, hA, h2,
                                              (unsigned*)hB, N);

    // ---- layer 2 ----
    gemm40_kernel<<<gN256, 256, 0, stream>>>(hB, W2, al2, ar2, hA, el, er, N);
    gat_agg1_kernel<<<gAgg, 256, 0, stream>>>(off_beg, off_end, csr, el, er, hA, logits, N);
}

// Round 12
// 335.716 us; speedup vs baseline: 1.1167x; 1.1167x over previous
//
#include <hip/hip_runtime.h>
#include <hip/hip_bf16.h>
#include <hip/hip_fp16.h>

#define NEG_SLOPE 0.2f
#define BW 256       // dst-nodes per bucket
#define MAXB 512     // max bucket count
#define BSTRIDE 4736 // fixed per-bucket region (mean 4092 + 10 sigma), Poisson-safe

typedef __attribute__((ext_vector_type(8))) short short8;
typedef __attribute__((ext_vector_type(4))) float f32x4;
typedef __attribute__((ext_vector_type(2))) float f32x2;
typedef __attribute__((ext_vector_type(4))) unsigned u32x4;

__device__ inline float bf2f(short s) {
    union { unsigned u; float f; } v;
    v.u = ((unsigned)(unsigned short)s) << 16;
    return v.f;
}
__device__ inline short f2bf(float f) {
    __hip_bfloat16 h = __float2bfloat16(f);
    return (short)*reinterpret_cast<unsigned short*>(&h);
}
__device__ inline float lo_bf(unsigned u) {
    union { unsigned u; float f; } v;
    v.u = u << 16;
    return v.f;
}
__device__ inline float hi_bf(unsigned u) {
    union { unsigned u; float f; } v;
    v.u = u & 0xFFFF0000u;
    return v.f;
}
// pack (src, p>=0) into one u32: src<<15 | (bf16 bits of p, sign dropped)
__device__ inline unsigned pack_sb(int s, float p) {
    union { float f; unsigned u; } v;
    v.f = p;
    return ((unsigned)s << 15) | ((v.u >> 16) & 0x7FFFu);
}
__device__ inline float unpack_b(unsigned u) {
    union { unsigned u; float f; } v;
    v.u = (u & 0x7FFFu) << 16;
    return v.f;
}
__device__ inline void gload16(const void* g, void* lds) {
    __builtin_amdgcn_global_load_lds((const __attribute__((address_space(1))) void*)g,
                                     (__attribute__((address_space(3))) void*)lds, 16, 0, 0);
}

// ---------------- K1: bucket partition (fixed-stride, single pass) + weight convert -------

__global__ __launch_bounds__(256) void bpart_cvt_kernel(
    const int* __restrict__ dst, const int* __restrict__ src, int* __restrict__ bcur,
    unsigned* __restrict__ tmp, int E, int NB, int GE,
    const float* __restrict__ W0, __hip_bfloat16* __restrict__ Wt0,
    const float* __restrict__ W1, __hip_bfloat16* __restrict__ Wt1) {
    int tid = threadIdx.x;
    if ((int)blockIdx.x >= GE) {
        int i = (blockIdx.x - GE) * 256 + tid;
        if (i < 256 * 128) {
            int k = i / 128, n = i % 128;
            Wt0[(size_t)n * 256 + k] = __float2bfloat16(W0[i]);
        } else if (i < 256 * 128 + 128 * 128) {
            int j = i - 256 * 128;
            int k = j / 128, n = j % 128;
            Wt1[(size_t)n * 128 + k] = __float2bfloat16(W1[j]);
        }
        return;
    }
    __shared__ int h[MAXB], h2[MAXB], base[MAXB];
    for (int i = tid; i < NB; i += 256) { h[i] = 0; h2[i] = 0; }
    __syncthreads();
    int e0 = blockIdx.x * 4096;
    unsigned pk[16];
    short bb[16];
#pragma unroll
    for (int i = 0; i < 16; ++i) {
        int e = e0 + i * 256 + tid;
        bool valid = e < E;
        int d = valid ? dst[e] : 0;
        int s = valid ? src[e] : 0;
        bb[i] = valid ? (short)(d >> 8) : (short)-1;
        pk[i] = (unsigned)s | ((unsigned)(d & 255) << 17);
        if (valid) atomicAdd(&h[d >> 8], 1);
    }
    __syncthreads();
    for (int i = tid; i < NB; i += 256)
        base[i] = h[i] ? (i * BSTRIDE + atomicAdd(&bcur[i], h[i])) : 0;
    __syncthreads();
#pragma unroll
    for (int i = 0; i < 16; ++i) {
        if (bb[i] >= 0) {
            int pos = base[bb[i]] + atomicAdd(&h2[bb[i]], 1);
            if (pos < (bb[i] + 1) * BSTRIDE) tmp[pos] = pk[i];  // clamp (Poisson 10-sigma)
        }
    }
}

// ---------------- shared GEMM body: C[M,128] = A[M,K] @ Bt[128,K]^T + fused el/er ----------

template <bool CVT_A>
__device__ void gemm_body(short* smem, int bm, const void* __restrict__ Av,
                          const __hip_bfloat16* __restrict__ Bt,
                          __hip_bfloat16* __restrict__ Cb,
                          const float* __restrict__ al, const float* __restrict__ ar,
                          float* __restrict__ el, float* __restrict__ er, int M, int K) {
    const int tid = threadIdx.x;
    const int lane = tid & 63;
    const int w = tid >> 6;
    const int wr = w >> 1, wc = w & 1;
    f32x4 acc[4][4];
#pragma unroll
    for (int m = 0; m < 4; ++m)
#pragma unroll
        for (int n = 0; n < 4; ++n) acc[m][n] = 0.f;

    for (int k0 = 0; k0 < K; k0 += 32) {
#pragma unroll
        for (int i = 0; i < 2; ++i) {
            const int c = (w * 2 + i) * 64 + lane;
            const int row = c >> 2;
            const int kpg = (c & 3) ^ (row & 3);
            int grow = bm + row;
            grow = grow < M ? grow : M - 1;
            if (CVT_A) {
                const float* gp = (const float*)Av + (size_t)grow * K + k0 + kpg * 8;
                f32x4 f0 = __builtin_nontemporal_load((const f32x4*)gp);
                f32x4 f1 = __builtin_nontemporal_load((const f32x4*)(gp + 4));
                short8 v;
                v[0] = f2bf(f0[0]); v[1] = f2bf(f0[1]); v[2] = f2bf(f0[2]); v[3] = f2bf(f0[3]);
                v[4] = f2bf(f1[0]); v[5] = f2bf(f1[1]); v[6] = f2bf(f1[2]); v[7] = f2bf(f1[3]);
                *(short8*)&smem[c * 8] = v;
            } else {
                const __hip_bfloat16* gp =
                    (const __hip_bfloat16*)Av + (size_t)grow * K + k0 + kpg * 8;
                gload16(gp, &smem[(w * 2 + i) * 512]);
            }
        }
#pragma unroll
        for (int i = 0; i < 2; ++i) {
            const int c = (w * 2 + i) * 64 + lane;
            const int col = c >> 2;
            const int kpg = (c & 3) ^ (col & 3);
            const __hip_bfloat16* gp = Bt + (size_t)col * K + k0 + kpg * 8;
            gload16(gp, &smem[4096 + (w * 2 + i) * 512]);
        }
        __syncthreads();
        short8 a[4], b[4];
        const int kp = lane >> 4;
#pragma unroll
        for (int m = 0; m < 4; ++m) {
            const int row = wr * 64 + m * 16 + (lane & 15);
            a[m] = *(const short8*)&smem[row * 32 + ((kp ^ (row & 3)) << 3)];
        }
#pragma unroll
        for (int n = 0; n < 4; ++n) {
            const int col = wc * 64 + n * 16 + (lane & 15);
            b[n] = *(const short8*)&smem[4096 + col * 32 + ((kp ^ (col & 3)) << 3)];
        }
#pragma unroll
        for (int m = 0; m < 4; ++m)
#pragma unroll
            for (int n = 0; n < 4; ++n)
                acc[m][n] = __builtin_amdgcn_mfma_f32_16x16x32_bf16(a[m], b[n], acc[m][n], 0, 0, 0);
        __syncthreads();
    }
    // ---- C store (bf16) ----
#pragma unroll
    for (int m = 0; m < 4; ++m)
#pragma unroll
        for (int j = 0; j < 4; ++j) {
            int row = bm + wr * 64 + m * 16 + (lane >> 4) * 4 + j;
            if (row >= M) continue;
#pragma unroll
            for (int n = 0; n < 4; ++n) {
                int col = wc * 64 + n * 16 + (lane & 15);
                Cb[(size_t)row * 128 + col] = __float2bfloat16(acc[m][n][j]);
            }
        }
    // ---- fused el/er epilogue ----
    const int lx = lane & 15;
    const float al00 = al[2 * wc * 32 + lx],        al01 = al[2 * wc * 32 + 16 + lx];
    const float al10 = al[(2 * wc + 1) * 32 + lx],  al11 = al[(2 * wc + 1) * 32 + 16 + lx];
    const float ar00 = ar[2 * wc * 32 + lx],        ar01 = ar[2 * wc * 32 + 16 + lx];
    const float ar10 = ar[(2 * wc + 1) * 32 + lx],  ar11 = ar[(2 * wc + 1) * 32 + 16 + lx];
#pragma unroll
    for (int m = 0; m < 4; ++m) {
#pragma unroll
        for (int j = 0; j < 4; ++j) {
            int row = bm + wr * 64 + m * 16 + (lane >> 4) * 4 + j;
            float pl0 = acc[m][0][j] * al00 + acc[m][1][j] * al01;
            float pr0 = acc[m][0][j] * ar00 + acc[m][1][j] * ar01;
            float pl1 = acc[m][2][j] * al10 + acc[m][3][j] * al11;
            float pr1 = acc[m][2][j] * ar10 + acc[m][3][j] * ar11;
#pragma unroll
            for (int off = 1; off < 16; off <<= 1) {
                pl0 += __shfl_xor(pl0, off);
                pr0 += __shfl_xor(pr0, off);
                pl1 += __shfl_xor(pl1, off);
                pr1 += __shfl_xor(pr1, off);
            }
            if (lx == 0 && row < M) {
                el[row * 4 + 2 * wc] = pl0;
                el[row * 4 + 2 * wc + 1] = pl1;
                er[row * 4 + 2 * wc] = pr0;
                er[row * 4 + 2 * wc + 1] = pr1;
            }
        }
    }
}

// ---------------- bsort body: per-bucket counting sort -> csr + off_beg/off_end ------------

__device__ void bsort_body(int* lds, int b, const unsigned* __restrict__ tmp,
                           const int* __restrict__ bcur, int* __restrict__ csr,
                           int* __restrict__ off_beg, int* __restrict__ off_end, int N) {
    int* cnt = lds;
    int* cur = lds + 256;
    int tid = threadIdx.x;
    int Rb = b * BSTRIDE;
    int cnt_b = bcur[b];
    if (cnt_b > BSTRIDE) cnt_b = BSTRIDE;
    int Rend = Rb + cnt_b;
    cnt[tid] = 0;
    __syncthreads();
    for (int i = Rb + tid; i < Rend; i += 256) atomicAdd(&cnt[tmp[i] >> 17], 1);
    __syncthreads();
    int v = cnt[tid];
    cur[tid] = v;
    __syncthreads();
    int x = v;
    for (int off = 1; off < 256; off <<= 1) {
        int y = (tid >= off) ? cur[tid - off] : 0;
        __syncthreads();
        x += y;
        cur[tid] = x;
        __syncthreads();
    }
    int excl = x - v;
    int g = b * BW + tid;
    int cbase = Rb + excl;
    if (g < N) {
        off_beg[g] = cbase;
        off_end[g] = cbase + v;
    }
    cur[tid] = cbase;
    __syncthreads();
    for (int i = Rb + tid; i < Rend; i += 256) {
        unsigned p = tmp[i];
        int pos = atomicAdd(&cur[p >> 17], 1);
        csr[pos] = (int)(p & 0x1FFFFu);
    }
}

// ---------------- K2: layer-0 GEMM (CVT_A) || bucket sort, one launch ----------------------

__global__ __launch_bounds__(256) void gemm0_bsort_kernel(
    const float* __restrict__ feats, const __hip_bfloat16* __restrict__ Wt0,
    __hip_bfloat16* __restrict__ Cb, const float* __restrict__ al,
    const float* __restrict__ ar, float* __restrict__ el, float* __restrict__ er,
    int M, int gM,
    const unsigned* __restrict__ tmp, const int* __restrict__ bcur, int* __restrict__ csr,
    int* __restrict__ off_beg, int* __restrict__ off_end, int N) {
    __shared__ __align__(16) short smem[8192];
    if ((int)blockIdx.x < gM) {
        gemm_body<true>(smem, blockIdx.x * 128, feats, Wt0, Cb, al, ar, el, er, M, 256);
    } else {
        bsort_body((int*)smem, blockIdx.x - gM, tmp, bcur, csr, off_beg, off_end, N);
    }
}

// ---------------- layer-1 GEMM ----------------

__global__ __launch_bounds__(256) void gemm1_kernel(
    const __hip_bfloat16* __restrict__ A, const __hip_bfloat16* __restrict__ Wt1,
    __hip_bfloat16* __restrict__ Cb, const float* __restrict__ al,
    const float* __restrict__ ar, float* __restrict__ el, float* __restrict__ er, int M) {
    __shared__ __align__(16) short smem[8192];
    gemm_body<false>(smem, blockIdx.x * 128, A, Wt1, Cb, al, ar, el, er, M, 128);
}

// ---------------- skinny GEMM layer2 + fused el/er: C[M,64], cols 40..63 unwritten ---------

__global__ __launch_bounds__(256) void gemm40_kernel(const __hip_bfloat16* __restrict__ A,
                                                     const float* __restrict__ W,
                                                     const float* __restrict__ al,
                                                     const float* __restrict__ ar,
                                                     __hip_bfloat16* __restrict__ C,
                                                     float* __restrict__ el,
                                                     float* __restrict__ er, int M) {
    int rowb = blockIdx.x * 256 + threadIdx.x;
    int row = rowb < M ? rowb : M - 1;
    float acc[40];
#pragma unroll
    for (int c = 0; c < 40; ++c) acc[c] = 0.f;
    const short8* ap = (const short8*)(A + (size_t)row * 128);
#pragma unroll 1
    for (int kc = 0; kc < 16; ++kc) {
        short8 v = ap[kc];
#pragma unroll
        for (int j = 0; j < 8; ++j) {
            float f = bf2f(v[j]);
            const float* wrow = W + (kc * 8 + j) * 40;
#pragma unroll
            for (int c = 0; c < 40; ++c) acc[c] += f * wrow[c];
        }
    }
    if (rowb < M) {
        float sl = 0.f, sr = 0.f;
#pragma unroll
        for (int c = 0; c < 40; ++c) {
            __hip_bfloat16 hb = __float2bfloat16(acc[c]);
            float hv = __bfloat162float(hb);
            C[(size_t)rowb * 64 + c] = hb;
            sl += hv * al[c];
            sr += hv * ar[c];
        }
        el[rowb] = sl;
        er[rowb] = sr;
    }
}

// ---------------- fused attention+aggregation, H=4 D=32, max-free, 16B/lane gathers --------
// edge phase: lane = es*4+ha (16 edges x 4 heads).
// consume: quarter q=lane>>4 handles edges e≡q (mod 4); ql=lane&15 covers cols ql*8..+7,
// head hq=ql>>2. Cross-quarter combine via shfl_xor(16),(32).

__global__ __launch_bounds__(256) void gat_agg4_kernel(
    const int* __restrict__ off_beg, const int* __restrict__ off_end,
    const int* __restrict__ csr_src, const float* __restrict__ el,
    const float* __restrict__ er, const __hip_bfloat16* __restrict__ hfeat,
    float* __restrict__ outf, unsigned* __restrict__ outb, int N) {
    int node = blockIdx.x * 4 + (threadIdx.x >> 6);
    if (node >= N) return;
    int lane = threadIdx.x & 63;
    int ha = lane & 3;
    int es = lane >> 2;
    int q = lane >> 4;
    int ql = lane & 15;
    int hq = ql >> 2;
    int beg = off_beg[node], end = off_end[node];
    float ern = er[node * 4 + ha];
    float d_acc = 0.f;
    float acc[8] = {0.f, 0.f, 0.f, 0.f, 0.f, 0.f, 0.f, 0.f};
    const __hip_bfloat16* hcol = hfeat + ql * 8;
    for (int base = beg; base < end; base += 16) {
        int b = base + es;
        bool valid = b < end;
        int s = valid ? csr_src[b] : 0;
        float x = -1e30f;
        if (valid) {
            x = el[s * 4 + ha] + ern;
            x = x > 0.f ? x : NEG_SLOPE * x;
        }
        float p = __expf(x);  // 0 for invalid edges
        float pv[4];
        int rv[4];
#pragma unroll
        for (int k = 0; k < 4; ++k) {
            int e = q + 4 * k;  // e <= 15
            pv[k] = __shfl(p, (e << 2) | hq);
            rv[k] = __shfl(s, e << 2);
        }
        u32x4 hv[4];
#pragma unroll
        for (int k = 0; k < 4; ++k)
            hv[k] = *(const u32x4*)(hcol + (size_t)rv[k] * 128);
#pragma unroll
        for (int k = 0; k < 4; ++k) {
            float a = pv[k];
            d_acc += a;
#pragma unroll
            for (int i = 0; i < 4; ++i) {
                acc[2 * i] += lo_bf(hv[k][i]) * a;
                acc[2 * i + 1] += hi_bf(hv[k][i]) * a;
            }
        }
    }
    // combine quarters
#pragma unroll
    for (int j = 0; j < 8; ++j) {
        acc[j] += __shfl_xor(acc[j], 16);
        acc[j] += __shfl_xor(acc[j], 32);
    }
    d_acc += __shfl_xor(d_acc, 16);
    d_acc += __shfl_xor(d_acc, 32);
    float idn = 1.f / fmaxf(d_acc, 1e-9f);
    if (q == 0) {
        float v[8];
#pragma unroll
        for (int j = 0; j < 8; ++j) {
            float t = acc[j] * idn;
            v[j] = t > 0.f ? t : __expf(t) - 1.f;  // ELU
        }
        f32x4 fo0 = {v[0], v[1], v[2], v[3]};
        f32x4 fo1 = {v[4], v[5], v[6], v[7]};
        __builtin_nontemporal_store(fo0, (f32x4*)(outf + (size_t)node * 128 + ql * 8));
        __builtin_nontemporal_store(fo1, (f32x4*)(outf + (size_t)node * 128 + ql * 8 + 4));
        u32x4 uo;
#pragma unroll
        for (int i = 0; i < 4; ++i)
            uo[i] = (unsigned)(unsigned short)f2bf(v[2 * i]) |
                    ((unsigned)(unsigned short)f2bf(v[2 * i + 1]) << 16);
        *(u32x4*)(outb + (size_t)node * 64 + ql * 4) = uo;
    }
}

// ---------------- fused attention+aggregation, H=1, max-free, table padded to 64 cols ------

__global__ __launch_bounds__(256) void gat_agg1_kernel(
    const int* __restrict__ off_beg, const int* __restrict__ off_end,
    const int* __restrict__ csr_src, const float* __restrict__ el,
    const float* __restrict__ er, const __hip_bfloat16* __restrict__ hfeat,
    float* __restrict__ logits, int N) {
    int node = blockIdx.x * 4 + (threadIdx.x >> 6);
    if (node >= N) return;
    int lane = threadIdx.x & 63;
    int cl = lane & 31;
    int half = lane >> 5;
    bool active = cl < 20;
    int beg = off_beg[node], end = off_end[node];
    float ern = er[node];
    float d_acc = 0.f;
    float acc0 = 0.f, acc1 = 0.f;
    const __hip_bfloat16* hcol = hfeat + cl * 2;
    for (int base = beg; base < end; base += 64) {
        int b = base + lane;
        bool valid = b < end;
        int s = valid ? csr_src[b] : 0;
        float x = -1e30f;
        if (valid) {
            x = el[s] + ern;
            x = x > 0.f ? x : NEG_SLOPE * x;
        }
        float p = __expf(x);  // 0 for invalid
        unsigned u_mine = pack_sb(s, p);
        int cnt = min(64, end - base);
        for (int sb = 0; sb < cnt; sb += 16) {
            unsigned uk[8];
#pragma unroll
            for (int k = 0; k < 8; ++k) {
                int e = sb + half + 2 * k;
                uk[k] = __shfl(u_mine, e & 63);
                if (e >= cnt) uk[k] &= ~0x7FFFu;  // alpha -> 0
            }
            unsigned hv[8];
#pragma unroll
            for (int k = 0; k < 8; ++k)
                hv[k] = active ? *(const unsigned*)(hcol + ((size_t)(uk[k] >> 15)) * 64) : 0u;
#pragma unroll
            for (int k = 0; k < 8; ++k) {
                float a = unpack_b(uk[k]);
                d_acc += a;
                acc0 += lo_bf(hv[k]) * a;
                acc1 += hi_bf(hv[k]) * a;
            }
        }
    }
    acc0 += __shfl_xor(acc0, 32);
    acc1 += __shfl_xor(acc1, 32);
    d_acc += __shfl_xor(d_acc, 32);
    float idn = 1.f / fmaxf(d_acc, 1e-9f);
    if (half == 0 && active) {
        f32x2 fo = {acc0 * idn, acc1 * idn};
        __builtin_nontemporal_store(fo, (f32x2*)(logits + (size_t)node * 40 + cl * 2));
    }
}

// ---------------- launch ----------------

extern "C" void kernel_launch(void* const* d_in, const int* in_sizes, int n_in,
                              void* d_out, int out_size, void* d_ws, size_t ws_size,
                              hipStream_t stream) {
    const float* feats = (const float*)d_in[0];
    const int* src = (const int*)d_in[1];
    const int* dst = (const int*)d_in[2];
    const float* W0 = (const float*)d_in[3];
    const float* al0 = (const float*)d_in[4];
    const float* ar0 = (const float*)d_in[5];
    const float* W1 = (const float*)d_in[6];
    const float* al1 = (const float*)d_in[7];
    const float* ar1 = (const float*)d_in[8];
    const float* W2 = (const float*)d_in[9];
    const float* al2 = (const float*)d_in[10];
    const float* ar2 = (const float*)d_in[11];

    const int N = in_sizes[0] / 256;
    const int E = in_sizes[1];
    const int NB = (N + BW - 1) / BW;

    float* out = (float*)d_out;
    float* logits = out;
    float* h1 = out + (size_t)N * 40;
    float* h2 = h1 + (size_t)N * 128;

    char* p = (char*)d_ws;
    __hip_bfloat16* hA = (__hip_bfloat16*)p; p += (size_t)N * 128 * 2;
    __hip_bfloat16* hB = (__hip_bfloat16*)p; p += (size_t)N * 128 * 2;
    float* el = (float*)p;   p += (size_t)N * 4 * 4;
    float* er = (float*)p;   p += (size_t)N * 4 * 4;
    __hip_bfloat16* Wt0 = (__hip_bfloat16*)p; p += 128 * 256 * 2;
    __hip_bfloat16* Wt1 = (__hip_bfloat16*)p; p += 128 * 128 * 2;
    int* off_beg = (int*)p;  p += (size_t)N * 4;
    int* off_end = (int*)p;  p += (size_t)N * 4;
    int* bcur = (int*)p;     p += MAXB * 4;
    int* csr = (int*)p;      p += (size_t)NB * BSTRIDE * 4;
    unsigned* tmp = (unsigned*)hB;  // alias: hB first written by agg4-L0, after bsort reads

    const int gN256 = (N + 255) / 256;
    const int gE4096 = (E + 4095) / 4096;  // 391
    const int gM128 = (N + 127) / 128;
    const int gAgg = (N + 3) / 4;
    const int gCvt = (256 * 128 + 128 * 128 + 255) / 256;  // 192

    // ---- K1: bucket partition (fixed stride) + weight convert ----
    hipError_t _e = hipMemsetAsync(bcur, 0, MAXB * sizeof(int), stream);
    (void)_e;
    bpart_cvt_kernel<<<gE4096 + gCvt, 256, 0, stream>>>(dst, src, bcur, tmp, E, NB, gE4096,
                                                        W0, Wt0, W1, Wt1);

    // ---- K2: layer-0 GEMM || bucket sort ----
    gemm0_bsort_kernel<<<gM128 + NB, 256, 0, stream>>>(feats, Wt0, hA, al0, ar0, el, er,
                                                       N, gM128, tmp, bcur, csr,
                                                       off_beg, off_end, N);

    // ---- layer 0 aggregate ----
    gat_agg4_kernel<<<gAgg, 256, 0, stream>>>(off_beg, off_end, csr, el, er, hA, h1,
                                              (unsigned*)hB, N);

    // ---- layer 1 ----
    gemm1_kernel<<<gM128, 256, 0, stream>>>(hB, Wt1, hA, al1, ar1, el, er, N);
    gat_agg4_kernel<<<gAgg, 256, 0, stream>>>(off_beg, off_end, csr, el, er, hA, h2,
                                              (unsigned*)hB, N);

    // ---- layer 2 ----
    gemm40_kernel<<<gN256, 256, 0, stream>>>(hB, W2, al2, ar2, hA, el, er, N);
    gat_agg1_kernel<<<gAgg, 256, 0, stream>>>(off_beg, off_end, csr, el, er, hA, logits, N);
}